// Round 6
// baseline (283.784 us; speedup 1.0000x reference)
//
#include <hip/hip_runtime.h>
#include <math.h>

// Problem constants (fixed by the reference)
constexpr int B     = 8;
constexpr int N_PER = 2048;
constexpr int C     = 256;
constexpr int KG    = 16;
constexpr int KTOP  = 512;
constexpr int KNN   = 32;
constexpr int N     = B * N_PER;   // 16384
constexpr float EPS = 1e-5f;

typedef __attribute__((ext_vector_type(8))) short  short8;   // 8 bf16 (4 VGPRs)
typedef __attribute__((ext_vector_type(4))) float  f32x4;    // MFMA acc frag

// ---------------------------------------------------------------------------
// Exact 3-way bf16 split: f = h + m + l + O(2^-27 |f|); subtractions exact.
// ---------------------------------------------------------------------------
__device__ inline void split3(float f, unsigned short& h, unsigned short& m,
                              unsigned short& l)
{
    const unsigned u  = __float_as_uint(f);
    const unsigned r1 = (u + 0x7FFFu + ((u >> 16) & 1u)) & 0xFFFF0000u;
    h = (unsigned short)(r1 >> 16);
    const float f2 = f - __uint_as_float(r1);
    const unsigned u2 = __float_as_uint(f2);
    const unsigned r2 = (u2 + 0x7FFFu + ((u2 >> 16) & 1u)) & 0xFFFF0000u;
    m = (unsigned short)(r2 >> 16);
    const float f3 = f2 - __uint_as_float(r2);
    const unsigned u3 = __float_as_uint(f3);
    l = (unsigned short)((u3 + 0x7FFFu + ((u3 >> 16) & 1u)) >> 16);
}

// split 8 contiguous floats (two float4) into three bf16x8 fragments
__device__ inline void split8(float4 a, float4 b,
                              short8& h8, short8& m8, short8& l8)
{
    float v[8] = {a.x, a.y, a.z, a.w, b.x, b.y, b.z, b.w};
    unsigned short hh, mm, ll;
#pragma unroll
    for (int j = 0; j < 8; ++j) {
        split3(v[j], hh, mm, ll);
        h8[j] = (short)hh;
        m8[j] = (short)mm;
        l8[j] = (short)ll;
    }
}

// ---------------------------------------------------------------------------
// K1 (MFMA, LDS-free): T = x @ thw.T ; R = x + x @ phw.T + (thb+phb) - T
//
// R5 (46us, PASS) was 79% overhead: split3 VALU between barriers (VALUBusy
// 28%), 3.1M LDS bank-conflict cycles, 2 barriers x 8 K-steps. This version
// deletes the LDS stage entirely: every A/B fragment is loaded global->reg
// at its per-lane address (weights L1/L2-resident; x L2/L3-resident; blocks
// sharing row0 share an XCD -> A panel ~3MB < 4MB XCD-L2) and split3'd
// in-register. No barriers, no LDS, no bank conflicts; latency hidden by
// 2 waves/SIMD and the 96-MFMA/step matrix-pipe workload.
//
// NUMERICS BITWISE-IDENTICAL to the passing R5 kernel: same split3 values,
// same per-accumulator MFMA order (hi term A1*B1 in its own accumulator;
// 5 cross terms in a separate lo accumulator), same epilogue arithmetic.
//
// BM=128 BN=64 BK=32, 4 waves 2x2, wave tile 64x32. grid (128,4).
// Fragment layouts (m89/m91-verified, R4-canary-confirmed):
//   A/B: row|col = lane&15, 8 contiguous K elems at k = (lane>>4)*8
//   C/D: col = lane&15, row = (lane>>4)*4 + reg
// ---------------------------------------------------------------------------
__global__ __launch_bounds__(256, 2) void k1_mfma_dual(
    const float* __restrict__ x, const float* __restrict__ thw,
    const float* __restrict__ phw, const float* __restrict__ thb,
    const float* __restrict__ phb, float* __restrict__ T, float* __restrict__ R)
{
    const int tid  = threadIdx.x;
    const int row0 = blockIdx.x * 128;
    const int n0   = blockIdx.y * 64;
    const int lane = tid & 63;
    const int wv   = tid >> 6;
    const int wr   = (wv >> 1) * 64;      // wave row offset within tile
    const int wc   = (wv & 1) * 32;       // wave col offset within tile
    const int fr   = lane & 15;
    const int fk   = (lane >> 4) * 8;     // k-offset of this lane's fragment

    // hi accumulators (A1*B1 only) and lo accumulators (all cross terms)
    f32x4 acTh[4][2], acTl[4][2], acQh[4][2], acQl[4][2];
    const f32x4 zz = {0.f, 0.f, 0.f, 0.f};
#pragma unroll
    for (int m = 0; m < 4; ++m)
#pragma unroll
        for (int n = 0; n < 2; ++n) {
            acTh[m][n] = zz; acTl[m][n] = zz;
            acQh[m][n] = zz; acQl[m][n] = zz;
        }

    // per-lane fragment base addresses
    const float* xBase = x   + (size_t)(row0 + wr + fr) * C + fk;
    const float* tBase = thw + (size_t)(n0 + wc + fr) * C + fk;
    const float* pBase = phw + (size_t)(n0 + wc + fr) * C + fk;

    for (int k0 = 0; k0 < C; k0 += 32) {
        // ---- A fragments: 4 m-slots x 3 split planes (in-register) ----
        short8 a1f[4], a2f[4], a3f[4];
#pragma unroll
        for (int m = 0; m < 4; ++m) {
            const float* p = xBase + m * 16 * C + k0;
            split8(*(const float4*)p, *(const float4*)(p + 4),
                   a1f[m], a2f[m], a3f[m]);
        }

        // ---- theta phase: load+split B_T frags, run all T MFMAs ----
        {
            short8 t1f[2], t2f[2], t3f[2];
#pragma unroll
            for (int n = 0; n < 2; ++n) {
                const float* p = tBase + n * 16 * C + k0;
                split8(*(const float4*)p, *(const float4*)(p + 4),
                       t1f[n], t2f[n], t3f[n]);
            }
            // group0 (hi B): A1->hi acc; A2,A3->lo acc
#pragma unroll
            for (int m = 0; m < 4; ++m)
#pragma unroll
                for (int n = 0; n < 2; ++n) {
                    acTh[m][n] = __builtin_amdgcn_mfma_f32_16x16x32_bf16(a1f[m], t1f[n], acTh[m][n], 0, 0, 0);
                    acTl[m][n] = __builtin_amdgcn_mfma_f32_16x16x32_bf16(a2f[m], t1f[n], acTl[m][n], 0, 0, 0);
                    acTl[m][n] = __builtin_amdgcn_mfma_f32_16x16x32_bf16(a3f[m], t1f[n], acTl[m][n], 0, 0, 0);
                }
            // group1 (mid B): A1,A2->lo acc
#pragma unroll
            for (int m = 0; m < 4; ++m)
#pragma unroll
                for (int n = 0; n < 2; ++n) {
                    acTl[m][n] = __builtin_amdgcn_mfma_f32_16x16x32_bf16(a1f[m], t2f[n], acTl[m][n], 0, 0, 0);
                    acTl[m][n] = __builtin_amdgcn_mfma_f32_16x16x32_bf16(a2f[m], t2f[n], acTl[m][n], 0, 0, 0);
                }
            // group2 (lo B): A1->lo acc
#pragma unroll
            for (int m = 0; m < 4; ++m)
#pragma unroll
                for (int n = 0; n < 2; ++n) {
                    acTl[m][n] = __builtin_amdgcn_mfma_f32_16x16x32_bf16(a1f[m], t3f[n], acTl[m][n], 0, 0, 0);
                }
        }

        // ---- phi phase: load+split B_P frags, run all Q MFMAs ----
        {
            short8 p1f[2], p2f[2], p3f[2];
#pragma unroll
            for (int n = 0; n < 2; ++n) {
                const float* p = pBase + n * 16 * C + k0;
                split8(*(const float4*)p, *(const float4*)(p + 4),
                       p1f[n], p2f[n], p3f[n]);
            }
#pragma unroll
            for (int m = 0; m < 4; ++m)
#pragma unroll
                for (int n = 0; n < 2; ++n) {
                    acQh[m][n] = __builtin_amdgcn_mfma_f32_16x16x32_bf16(a1f[m], p1f[n], acQh[m][n], 0, 0, 0);
                    acQl[m][n] = __builtin_amdgcn_mfma_f32_16x16x32_bf16(a2f[m], p1f[n], acQl[m][n], 0, 0, 0);
                    acQl[m][n] = __builtin_amdgcn_mfma_f32_16x16x32_bf16(a3f[m], p1f[n], acQl[m][n], 0, 0, 0);
                }
#pragma unroll
            for (int m = 0; m < 4; ++m)
#pragma unroll
                for (int n = 0; n < 2; ++n) {
                    acQl[m][n] = __builtin_amdgcn_mfma_f32_16x16x32_bf16(a1f[m], p2f[n], acQl[m][n], 0, 0, 0);
                    acQl[m][n] = __builtin_amdgcn_mfma_f32_16x16x32_bf16(a2f[m], p2f[n], acQl[m][n], 0, 0, 0);
                }
#pragma unroll
            for (int m = 0; m < 4; ++m)
#pragma unroll
                for (int n = 0; n < 2; ++n) {
                    acQl[m][n] = __builtin_amdgcn_mfma_f32_16x16x32_bf16(a1f[m], p3f[n], acQl[m][n], 0, 0, 0);
                }
        }
    }

    // epilogue: T = hi + lo; R = x + (qhi + qlo) + (thb+phb) - T
    const int cr = (lane >> 4) * 4;
#pragma unroll
    for (int m = 0; m < 4; ++m) {
#pragma unroll
        for (int n = 0; n < 2; ++n) {
            const int col  = n0 + wc + n * 16 + fr;
            const float bias = thb[col] + phb[col];
#pragma unroll
            for (int j = 0; j < 4; ++j) {
                const int row = row0 + wr + m * 16 + cr + j;
                const size_t off = (size_t)row * C + col;
                const float tval = acTh[m][n][j] + acTl[m][n][j];
                const float qval = acQh[m][n][j] + acQl[m][n][j];
                T[off] = tval;
                R[off] = x[off] + qval + bias - tval;
            }
        }
    }
}

// ---------------------------------------------------------------------------
// K2a: x1[i] = max_k T[src[i,k]] + R[i].
// batch = blockIdx & 7: with round-robin block->XCD dispatch each XCD's 4MB L2
// caches exactly its batch's 2MB T-slab, so the 16-way gather re-reads hit L2.
// grid N/4 = 4096, block 256 (4 nodes/block, one node per wave, float4 lanes).
// ---------------------------------------------------------------------------
__global__ __launch_bounds__(256) void k2a_gather_max(
    const int* __restrict__ esrc, const float* __restrict__ T, float* x1r)
{
    const int gb = blockIdx.x;
    const int b  = gb & 7;                    // batch -> XCD (L2 locality)
    const int node0 = b * N_PER + (gb >> 3) * 4;
    const int t = threadIdx.x;
    __shared__ int s[4][KG];
    if (t < 64) s[t >> 4][t & 15] = esrc[(node0 + (t >> 4)) * KG + (t & 15)];
    __syncthreads();
    const int m  = t >> 6;
    const int c4 = (t & 63) * 4;
    float4 acc = make_float4(-INFINITY, -INFINITY, -INFINITY, -INFINITY);
#pragma unroll
    for (int k = 0; k < KG; ++k) {
        const float4 v = *(const float4*)&T[(size_t)s[m][k] * C + c4];
        acc.x = fmaxf(acc.x, v.x);  acc.y = fmaxf(acc.y, v.y);
        acc.z = fmaxf(acc.z, v.z);  acc.w = fmaxf(acc.w, v.w);
    }
    const size_t off = (size_t)(node0 + m) * C + c4;
    float4 r = *(const float4*)&x1r[off];
    r.x += acc.x;  r.y += acc.y;  r.z += acc.z;  r.w += acc.w;
    *(float4*)&x1r[off] = r;
}

// ---------------------------------------------------------------------------
// K2bc: fused score MLP. Per block: 64 nodes.
// ---------------------------------------------------------------------------
__global__ __launch_bounds__(256) void k2bc_score(
    const float* __restrict__ x1, const float* __restrict__ w1,
    const float* __restrict__ b1, const float* __restrict__ g1,
    const float* __restrict__ be1, const float* __restrict__ m1,
    const float* __restrict__ v1,
    const float* __restrict__ w2, const float* __restrict__ b2,
    const float* __restrict__ g2, const float* __restrict__ be2,
    const float* __restrict__ m2, const float* __restrict__ v2,
    const float* __restrict__ w3, const float* __restrict__ b3,
    float* __restrict__ score_ws, float* __restrict__ out_score)
{
    constexpr int BK = 16, ST = 68;
    __shared__ float Xs[BK * ST];
    __shared__ float Ws[BK * ST];
    __shared__ float t1s[64 * 65];
    __shared__ float w2s[32 * 65];
    __shared__ float w3s[32];
    __shared__ float zs[64 * 33];
    const int tid  = threadIdx.x;
    const int row0 = blockIdx.x * 64;
    const int tx = tid & 15, ty = tid >> 4;
    const int lm = tid >> 2, lq = (tid & 3) << 2;

    float acc[4][4] = {{0.f}};
    for (int k0 = 0; k0 < C; k0 += BK) {
        float4 fx = *(const float4*)(x1 + (size_t)(row0 + lm) * C + k0 + lq);
        float4 fw = *(const float4*)(w1 + (size_t)lm * C + k0 + lq);
        __syncthreads();
        Xs[(lq + 0) * ST + lm] = fx.x;  Xs[(lq + 1) * ST + lm] = fx.y;
        Xs[(lq + 2) * ST + lm] = fx.z;  Xs[(lq + 3) * ST + lm] = fx.w;
        Ws[(lq + 0) * ST + lm] = fw.x;  Ws[(lq + 1) * ST + lm] = fw.y;
        Ws[(lq + 2) * ST + lm] = fw.z;  Ws[(lq + 3) * ST + lm] = fw.w;
        __syncthreads();
#pragma unroll
        for (int k = 0; k < BK; ++k) {
            float4 a4 = *(const float4*)&Xs[k * ST + (ty << 2)];
            float4 w4 = *(const float4*)&Ws[k * ST + (tx << 2)];
            float av[4] = {a4.x, a4.y, a4.z, a4.w};
            float wv[4] = {w4.x, w4.y, w4.z, w4.w};
#pragma unroll
            for (int i2 = 0; i2 < 4; ++i2)
#pragma unroll
                for (int j2 = 0; j2 < 4; ++j2) acc[i2][j2] += av[i2] * wv[j2];
        }
    }
    __syncthreads();
#pragma unroll
    for (int i2 = 0; i2 < 4; ++i2) {
        const int mrow = (ty << 2) + i2;
#pragma unroll
        for (int j2 = 0; j2 < 4; ++j2) {
            const int o = (tx << 2) + j2;
            float y = acc[i2][j2] + b1[o];
            y = fmaxf(y, 0.f);
            y = (y - m1[o]) * (1.0f / sqrtf(v1[o] + EPS)) * g1[o] + be1[o];
            t1s[mrow * 65 + o] = y;
        }
    }
    for (int idx = tid; idx < 2048; idx += 256)
        w2s[(idx >> 6) * 65 + (idx & 63)] = w2[idx];
    if (tid < 32) w3s[tid] = w3[tid];
    __syncthreads();

    const int o = tid & 31;
    const float inv2 = (1.0f / sqrtf(v2[o] + EPS)) * g2[o];
#pragma unroll
    for (int p = 0; p < 8; ++p) {
        const int nl = p * 8 + (tid >> 5);
        float z = 0.f;
#pragma unroll
        for (int j = 0; j < 64; ++j) z += t1s[nl * 65 + j] * w2s[o * 65 + j];
        z += b2[o];
        z = fmaxf(z, 0.f);
        z = (z - m2[o]) * inv2 + be2[o];
        zs[nl * 33 + o] = z;
    }
    __syncthreads();

    if (tid < 64) {
        float sacc = 0.f;
#pragma unroll
        for (int j = 0; j < 32; ++j) sacc += zs[tid * 33 + j] * w3s[j];
        sacc += b3[0];
        const int node = row0 + tid;
        score_ws[node]  = sacc;
        out_score[node] = sacc;
    }
}

// ---------------------------------------------------------------------------
// K3: per-batch top-512 of 2048, descending, ties -> lower index first.
// Epilogue also writes xsel (selected xyz) so k5 can stage coalesced.
// ---------------------------------------------------------------------------
__global__ __launch_bounds__(1024) void k3_topk(
    const float* __restrict__ score, const float* __restrict__ xyz,
    float* __restrict__ out_topk, int* __restrict__ perm,
    float* __restrict__ xsel)
{
    __shared__ unsigned long long keys[N_PER];
    const int b = blockIdx.x;
    const int t = threadIdx.x;
    for (int i = t; i < N_PER; i += 1024) {
        const float v = score[b * N_PER + i];
        unsigned u = __float_as_uint(v);
        const unsigned ua = (u & 0x80000000u) ? ~u : (u | 0x80000000u);
        const unsigned ud = ~ua;   // descending-monotone
        keys[i] = ((unsigned long long)ud << 32) | (unsigned)i;
    }
    __syncthreads();
    for (int k = 2; k <= N_PER; k <<= 1) {
        for (int j = k >> 1; j > 0; j >>= 1) {
            for (int i = t; i < N_PER; i += 1024) {
                const int ixj = i ^ j;
                if (ixj > i) {
                    const unsigned long long a = keys[i], c = keys[ixj];
                    const bool up = ((i & k) == 0);
                    if ((a > c) == up) { keys[i] = c; keys[ixj] = a; }
                }
            }
            __syncthreads();
        }
    }
    for (int r = t; r < KTOP; r += 1024) {
        const int idx = (int)(keys[r] & 0xffffffffu);
        const int g = b * N_PER + idx;
        out_topk[b * KTOP + r] = score[g];
        perm[b * KTOP + r] = g;
        xsel[(b * KTOP + r) * 3 + 0] = xyz[g * 3 + 0];
        xsel[(b * KTOP + r) * 3 + 1] = xyz[g * 3 + 1];
        xsel[(b * KTOP + r) * 3 + 2] = xyz[g * 3 + 2];
    }
}

// ---------------------------------------------------------------------------
// K5: fused gather (x_new/x_copy) + 32-NN among 512 selected points.
// xyz staged coalesced from xsel (contiguous 6KB per batch).
// grid B*KTOP/4 = 1024, block 256.
// ---------------------------------------------------------------------------
__global__ __launch_bounds__(256) void k5_knn(
    const int* __restrict__ perm, const float* __restrict__ xsel,
    const float* __restrict__ x1, const float* __restrict__ xorig,
    float* __restrict__ out_xnew, float* __restrict__ out_xcopy,
    float* __restrict__ out_knn)
{
    constexpr int G = 4;
    __shared__ float px[KTOP], py[KTOP], pz[KTOP];
    __shared__ unsigned long long keys[G * KTOP];
    const int t  = threadIdx.x;
    const int q0 = blockIdx.x * G;
    const int b  = q0 >> 9;
    const int i0 = q0 & 511;

    for (int idx = t; idx < KTOP; idx += 256) {
        const size_t base = ((size_t)b * KTOP + idx) * 3;
        px[idx] = xsel[base + 0];
        py[idx] = xsel[base + 1];
        pz[idx] = xsel[base + 2];
    }
#pragma unroll
    for (int p = 0; p < G; ++p) {
        const int row = q0 + p;
        const int g = perm[row];
        out_xnew [(size_t)row * C + t] = x1   [(size_t)g * C + t];
        out_xcopy[(size_t)row * C + t] = xorig[(size_t)g * C + t];
    }
    __syncthreads();

    for (int w = t; w < G * KTOP; w += 256) {
        const int p = w >> 9, idx = w & 511;
        const float dx = __fsub_rn(px[i0 + p], px[idx]);
        const float dy = __fsub_rn(py[i0 + p], py[idx]);
        const float dz = __fsub_rn(pz[i0 + p], pz[idx]);
        const float d2 = __fadd_rn(__fadd_rn(__fmul_rn(dx, dx), __fmul_rn(dy, dy)),
                                   __fmul_rn(dz, dz));
        keys[w] = ((unsigned long long)__float_as_uint(d2) << 32) | (unsigned)idx;
    }
    __syncthreads();

    for (int k = 2; k <= 32; k <<= 1) {
        for (int j = k >> 1; j > 0; j >>= 1) {
            for (int i = t; i < G * KTOP; i += 256) {
                const int ixj = i ^ j;
                if (ixj > i) {
                    const int il = i & 31;
                    const unsigned long long a = keys[i], c = keys[ixj];
                    const bool up = ((il & k) == 0) || (k == 32);
                    if ((a > c) == up) { keys[i] = c; keys[ixj] = a; }
                }
            }
            __syncthreads();
        }
    }
    for (int r = 0; r < 4; ++r) {
        const int npairs = 8 >> r;
        const int total  = G * npairs * 32;
        for (int w = t; w < total; w += 256) {
            const int p  = w / (npairs * 32);
            const int rm = w - p * (npairs * 32);
            const int m  = rm >> 5, i = rm & 31;
            const int baseA = p * KTOP + m * (64 << r);
            const int baseB = baseA + (32 << r);
            const unsigned long long a = keys[baseA + i];
            const unsigned long long c = keys[baseB + 31 - i];
            keys[baseA + i] = (c < a) ? c : a;
        }
        __syncthreads();
        for (int j = 16; j > 0; j >>= 1) {
            for (int w = t; w < total; w += 256) {
                const int p  = w / (npairs * 32);
                const int rm = w - p * (npairs * 32);
                const int m  = rm >> 5, i = rm & 31;
                const int ixj = i ^ j;
                if (ixj > i) {
                    const int baseA = p * KTOP + m * (64 << r);
                    const unsigned long long a = keys[baseA + i], c = keys[baseA + ixj];
                    if (a > c) { keys[baseA + i] = c; keys[baseA + ixj] = a; }
                }
            }
            __syncthreads();
        }
    }

    if (t < G * KNN) {
        const int p = t >> 5, r = t & 31;
        out_knn[((size_t)(q0 + p)) * KNN + r] =
            (float)(unsigned)(keys[p * KTOP + r] & 0xffffffffu);
    }
}

// ---------------------------------------------------------------------------
extern "C" void kernel_launch(void* const* d_in, const int* in_sizes, int n_in,
                              void* d_out, int out_size, void* d_ws, size_t ws_size,
                              hipStream_t stream)
{
    const float* x     = (const float*)d_in[0];
    const float* xorig = (const float*)d_in[1];
    const float* xyz   = (const float*)d_in[2];
    const int*   esrc  = (const int*)d_in[3];
    const float* thw = (const float*)d_in[5];
    const float* thb = (const float*)d_in[6];
    const float* phw = (const float*)d_in[7];
    const float* phb = (const float*)d_in[8];
    const float* w1  = (const float*)d_in[9];
    const float* b1  = (const float*)d_in[10];
    const float* g1  = (const float*)d_in[11];
    const float* be1 = (const float*)d_in[12];
    const float* m1  = (const float*)d_in[13];
    const float* v1  = (const float*)d_in[14];
    const float* w2  = (const float*)d_in[15];
    const float* b2  = (const float*)d_in[16];
    const float* g2  = (const float*)d_in[17];
    const float* be2 = (const float*)d_in[18];
    const float* m2  = (const float*)d_in[19];
    const float* v2  = (const float*)d_in[20];
    const float* w3  = (const float*)d_in[21];
    const float* b3  = (const float*)d_in[22];

    float* ws   = (float*)d_ws;
    float* T    = ws;                          // N*C
    float* x1   = ws + (size_t)N * C;          // N*C  (R from k1, becomes x1)
    float* sc   = ws + 2 * (size_t)N * C;      // N
    int*   perm = (int*)(sc + N);              // B*KTOP
    float* xsel = (float*)(perm + B * KTOP);   // B*KTOP*3

    float* out     = (float*)d_out;
    float* o_knn   = out;                                  // B*KTOP*KNN
    float* o_xnew  = o_knn + (size_t)B * KTOP * KNN;       // B*KTOP*C
    float* o_xcopy = o_xnew + (size_t)B * KTOP * C;        // B*KTOP*C
    float* o_score = o_xcopy + (size_t)B * KTOP * C;       // B*N_PER
    float* o_topk  = o_score + (size_t)B * N_PER;          // B*KTOP

    k1_mfma_dual<<<dim3(N / 128, C / 64), 256, 0, stream>>>(x, thw, phw, thb, phb, T, x1);
    k2a_gather_max<<<N / 4, 256, 0, stream>>>(esrc, T, x1);
    k2bc_score<<<N / 64, 256, 0, stream>>>(x1, w1, b1, g1, be1, m1, v1,
                                           w2, b2, g2, be2, m2, v2, w3, b3, sc, o_score);
    k3_topk<<<B, 1024, 0, stream>>>(sc, xyz, o_topk, perm, xsel);
    k5_knn<<<B * KTOP / 4, 256, 0, stream>>>(perm, xsel, x1, xorig,
                                             o_xnew, o_xcopy, o_knn);
}